// Round 2
// baseline (432.909 us; speedup 1.0000x reference)
//
#include <hip/hip_runtime.h>
#include <math.h>

#define N_NODES 50000
#define N_EDGES 800000

// ---------------- utility ----------------
__global__ void zero_int_kernel(int* __restrict__ p, int n) {
    int i = blockIdx.x * blockDim.x + threadIdx.x;
    if (i < n) p[i] = 0;
}

// counts[dst] += 1 for every edge (self-loops added analytically later)
__global__ void count_kernel(const int* __restrict__ ei, int* __restrict__ counts) {
    int i = blockIdx.x * blockDim.x + threadIdx.x;
    if (i < N_EDGES) {
        int dst = ei[N_EDGES + i];
        atomicAdd(&counts[dst], 1);
    }
}

#define SCAN_T 1024
#define SCAN_ITEMS 49  // 1024*49 = 50176 >= 50000

// single-block exclusive scan of counts -> off; also dinv[n] = rsqrt(deg+1)
// NOTE: no per-thread array — counts is read twice (L2-resident) to avoid
// runtime-indexed local storage going to scratch (that cost 116 us in R1).
__global__ void scan_kernel(const int* __restrict__ counts, int* __restrict__ off,
                            float* __restrict__ dinv) {
    __shared__ int sums[SCAN_T];
    int t = threadIdx.x;
    int base = t * SCAN_ITEMS;

    int run = 0;
#pragma unroll
    for (int i = 0; i < SCAN_ITEMS; i++) {
        int idx = base + i;
        if (idx < N_NODES) run += counts[idx];
    }
    sums[t] = run;
    __syncthreads();
    for (int o = 1; o < SCAN_T; o <<= 1) {
        int v = (t >= o) ? sums[t - o] : 0;
        __syncthreads();
        if (t >= o) sums[t] += v;
        __syncthreads();
    }
    int carry = (t > 0) ? sums[t - 1] : 0;
#pragma unroll
    for (int i = 0; i < SCAN_ITEMS; i++) {
        int idx = base + i;
        if (idx < N_NODES) {
            int c = counts[idx];
            off[idx] = carry;
            dinv[idx] = rsqrtf((float)(c + 1));
            carry += c;
        }
    }
    if (t == SCAN_T - 1) off[N_NODES] = sums[SCAN_T - 1];
}

// scatter edges into CSR grouped by dst
__global__ void fill_kernel(const int* __restrict__ ei, const int* __restrict__ off,
                            int* __restrict__ cursor, int* __restrict__ csr_src) {
    int i = blockIdx.x * blockDim.x + threadIdx.x;
    if (i < N_EDGES) {
        int src = ei[i];
        int dst = ei[N_EDGES + i];
        int pos = off[dst] + atomicAdd(&cursor[dst], 1);
        csr_src[pos] = src;
    }
}

// ---------------- GEMM: H[N,C_OUT] = X[N,128] @ W[128,C_OUT] ----------------
template <int C_OUT>
__global__ __launch_bounds__(256) void gemm_kernel(const float* __restrict__ X,
                                                   const float* __restrict__ W,
                                                   float* __restrict__ H) {
    constexpr int K = 128;
    constexpr int ROWS = 32;
    constexpr int GPT = 256 / C_OUT;  // column groups per block: 2 (C=128) or 4 (C=64)
    constexpr int RPG = ROWS / GPT;   // rows per thread: 16 or 8
    __shared__ float xs[ROWS][K];     // 16 KB

    int t = threadIdx.x;
    int rowbase = blockIdx.x * ROWS;

    // cooperative load of the 32x128 x-tile (1024 float4, 4 per thread, coalesced)
#pragma unroll
    for (int i = 0; i < 4; i++) {
        int f = i * 256 + t;  // float4 index within tile
        int r = f >> 5;       // 32 float4 per row
        int kk = f & 31;
        float4 v;
        int grow = rowbase + r;
        if (grow < N_NODES) {
            v = reinterpret_cast<const float4*>(X + (size_t)grow * K)[kk];
        } else {
            v = make_float4(0.f, 0.f, 0.f, 0.f);
        }
        reinterpret_cast<float4*>(&xs[r][0])[kk] = v;
    }
    __syncthreads();

    int col = t % C_OUT;
    int g = t / C_OUT;  // uniform per wave
    int r0 = g * RPG;

    float acc[RPG];
#pragma unroll
    for (int r = 0; r < RPG; r++) acc[r] = 0.f;

    for (int kk = 0; kk < K / 4; kk++) {
        float w0 = W[(4 * kk + 0) * C_OUT + col];
        float w1 = W[(4 * kk + 1) * C_OUT + col];
        float w2 = W[(4 * kk + 2) * C_OUT + col];
        float w3 = W[(4 * kk + 3) * C_OUT + col];
#pragma unroll
        for (int r = 0; r < RPG; r++) {
            float4 xv = reinterpret_cast<const float4*>(&xs[r0 + r][0])[kk];
            acc[r] = fmaf(xv.x, w0, acc[r]);
            acc[r] = fmaf(xv.y, w1, acc[r]);
            acc[r] = fmaf(xv.z, w2, acc[r]);
            acc[r] = fmaf(xv.w, w3, acc[r]);
        }
    }

#pragma unroll
    for (int r = 0; r < RPG; r++) {
        int grow = rowbase + r0 + r;
        if (grow < N_NODES) H[(size_t)grow * C_OUT + col] = acc[r];
    }
}

// ---------------- aggregation: OUT[n] = dinv[n]*(dinv[n]*H[n] + sum_e dinv[s]*H[s]) + b
template <int C, bool RELU>
__global__ __launch_bounds__(256) void agg_kernel(const float* __restrict__ H,
                                                  const int* __restrict__ off,
                                                  const int* __restrict__ csr_src,
                                                  const float* __restrict__ dinv,
                                                  const float* __restrict__ bias,
                                                  float* __restrict__ OUT) {
    int wave = threadIdx.x >> 6;
    int lane = threadIdx.x & 63;
    int n = blockIdx.x * 4 + wave;
    if (n >= N_NODES) return;

    float dn = dinv[n];
    int e0 = off[n];
    int e1 = off[n + 1];

    if constexpr (C == 128) {
        int c = lane * 2;
        float2 h = reinterpret_cast<const float2*>(H + (size_t)n * C)[lane];
        float2 acc;
        acc.x = dn * h.x;  // self-loop (inner weight dinv[n], outer dn applied later)
        acc.y = dn * h.y;
        for (int e = e0; e < e1; e++) {
            int s = csr_src[e];
            float ds = dinv[s];
            float2 hs = reinterpret_cast<const float2*>(H + (size_t)s * C)[lane];
            acc.x = fmaf(ds, hs.x, acc.x);
            acc.y = fmaf(ds, hs.y, acc.y);
        }
        acc.x = fmaf(acc.x, dn, bias[c]);
        acc.y = fmaf(acc.y, dn, bias[c + 1]);
        if (RELU) {
            acc.x = fmaxf(acc.x, 0.f);
            acc.y = fmaxf(acc.y, 0.f);
        }
        reinterpret_cast<float2*>(OUT + (size_t)n * C)[lane] = acc;
    } else {
        // C == 64: one channel per lane
        float h = H[(size_t)n * C + lane];
        float acc = dn * h;
        for (int e = e0; e < e1; e++) {
            int s = csr_src[e];
            float ds = dinv[s];
            acc = fmaf(ds, H[(size_t)s * C + lane], acc);
        }
        acc = fmaf(acc, dn, bias[lane]);
        if (RELU) acc = fmaxf(acc, 0.f);
        OUT[(size_t)n * C + lane] = acc;
    }
}

// ---------------- launch ----------------
extern "C" void kernel_launch(void* const* d_in, const int* in_sizes, int n_in,
                              void* d_out, int out_size, void* d_ws, size_t ws_size,
                              hipStream_t stream) {
    const float* x  = (const float*)d_in[0];
    const int*   ei = (const int*)d_in[1];
    const float* W1 = (const float*)d_in[2];
    const float* b1 = (const float*)d_in[3];
    const float* W2 = (const float*)d_in[4];
    const float* b2 = (const float*)d_in[5];
    float* out = (float*)d_out;

    char* ws = (char*)d_ws;
    auto alloc = [&](size_t bytes) -> char* {
        char* p = ws;
        ws += (bytes + 255) / 256 * 256;
        return p;
    };
    int* cnt_cur = (int*)alloc((size_t)2 * N_NODES * 4);  // counts | cursor, contiguous
    int* counts = cnt_cur;
    int* cursor = cnt_cur + N_NODES;
    int* off = (int*)alloc((size_t)(N_NODES + 1) * 4);
    int* csr = (int*)alloc((size_t)N_EDGES * 4);
    float* dinv = (float*)alloc((size_t)N_NODES * 4);
    float* h1 = (float*)alloc((size_t)N_NODES * 128 * 4);
    float* g1 = (float*)alloc((size_t)N_NODES * 128 * 4);
    float* h2 = h1;  // layer-1 GEMM output no longer needed after agg1

    zero_int_kernel<<<(2 * N_NODES + 255) / 256, 256, 0, stream>>>(cnt_cur, 2 * N_NODES);
    count_kernel<<<(N_EDGES + 255) / 256, 256, 0, stream>>>(ei, counts);
    scan_kernel<<<1, SCAN_T, 0, stream>>>(counts, off, dinv);
    fill_kernel<<<(N_EDGES + 255) / 256, 256, 0, stream>>>(ei, off, cursor, csr);

    gemm_kernel<128><<<(N_NODES + 31) / 32, 256, 0, stream>>>(x, W1, h1);
    agg_kernel<128, true><<<(N_NODES + 3) / 4, 256, 0, stream>>>(h1, off, csr, dinv, b1, g1);
    gemm_kernel<64><<<(N_NODES + 31) / 32, 256, 0, stream>>>(g1, W2, h2);
    agg_kernel<64, false><<<(N_NODES + 3) / 4, 256, 0, stream>>>(h2, off, csr, dinv, b2, out);
}

// Round 3
// 326.506 us; speedup vs baseline: 1.3259x; 1.3259x over previous
//
#include <hip/hip_runtime.h>
#include <math.h>

#define N_NODES 50000
#define N_EDGES 800000

// ---------------- utility ----------------
__global__ void zero_int_kernel(int* __restrict__ p, int n) {
    int i = blockIdx.x * blockDim.x + threadIdx.x;
    if (i < n) p[i] = 0;
}

// counts[dst] += 1 for every edge (self-loops added analytically later)
__global__ void count_kernel(const int* __restrict__ ei, int* __restrict__ counts) {
    int i = blockIdx.x * blockDim.x + threadIdx.x;
    if (i < N_EDGES) {
        int dst = ei[N_EDGES + i];
        atomicAdd(&counts[dst], 1);
    }
}

// Allocate disjoint CSR ranges: off[i] = global cursor bump by counts[i].
// No ordered prefix sum needed — ranges just have to be disjoint & contiguous.
// Wave shuffle-scan + one atomic per block (196 total). Also emits dinv.
__global__ __launch_bounds__(256) void alloc_kernel(const int* __restrict__ counts,
                                                    int* __restrict__ off,
                                                    float* __restrict__ dinv,
                                                    int* __restrict__ total) {
    __shared__ int wsum[4];
    __shared__ int wbase[4];
    int t = threadIdx.x;
    int lane = t & 63;
    int w = t >> 6;
    int i = blockIdx.x * 256 + t;
    int c = (i < N_NODES) ? counts[i] : 0;

    // inclusive wave scan of c
    int incl = c;
#pragma unroll
    for (int o = 1; o < 64; o <<= 1) {
        int v = __shfl_up(incl, o, 64);
        if (lane >= o) incl += v;
    }
    if (lane == 63) wsum[w] = incl;  // wave total
    __syncthreads();
    if (t == 0) {
        int s0 = wsum[0], s1 = wsum[1], s2 = wsum[2], s3 = wsum[3];
        int base = atomicAdd(total, s0 + s1 + s2 + s3);
        wbase[0] = base;
        wbase[1] = base + s0;
        wbase[2] = base + s0 + s1;
        wbase[3] = base + s0 + s1 + s2;
    }
    __syncthreads();
    if (i < N_NODES) {
        off[i] = wbase[w] + incl - c;  // exclusive within wave
        dinv[i] = rsqrtf((float)(c + 1));
    }
}

// scatter edges into CSR grouped by dst
__global__ void fill_kernel(const int* __restrict__ ei, const int* __restrict__ off,
                            int* __restrict__ cursor, int* __restrict__ csr_src) {
    int i = blockIdx.x * blockDim.x + threadIdx.x;
    if (i < N_EDGES) {
        int src = ei[i];
        int dst = ei[N_EDGES + i];
        int pos = off[dst] + atomicAdd(&cursor[dst], 1);
        csr_src[pos] = src;
    }
}

// ---------------- GEMM: H[N,C_OUT] = X[N,128] @ W[128,C_OUT] ----------------
template <int C_OUT>
__global__ __launch_bounds__(256) void gemm_kernel(const float* __restrict__ X,
                                                   const float* __restrict__ W,
                                                   float* __restrict__ H) {
    constexpr int K = 128;
    constexpr int ROWS = 32;
    constexpr int GPT = 256 / C_OUT;  // column groups per block: 2 (C=128) or 4 (C=64)
    constexpr int RPG = ROWS / GPT;   // rows per thread: 16 or 8
    __shared__ float xs[ROWS][K];     // 16 KB

    int t = threadIdx.x;
    int rowbase = blockIdx.x * ROWS;

    // cooperative load of the 32x128 x-tile (1024 float4, 4 per thread, coalesced)
#pragma unroll
    for (int i = 0; i < 4; i++) {
        int f = i * 256 + t;  // float4 index within tile
        int r = f >> 5;       // 32 float4 per row
        int kk = f & 31;
        float4 v;
        int grow = rowbase + r;
        if (grow < N_NODES) {
            v = reinterpret_cast<const float4*>(X + (size_t)grow * K)[kk];
        } else {
            v = make_float4(0.f, 0.f, 0.f, 0.f);
        }
        reinterpret_cast<float4*>(&xs[r][0])[kk] = v;
    }
    __syncthreads();

    int col = t % C_OUT;
    int g = t / C_OUT;  // uniform per wave
    int r0 = g * RPG;

    float acc[RPG];
#pragma unroll
    for (int r = 0; r < RPG; r++) acc[r] = 0.f;

    for (int kk = 0; kk < K / 4; kk++) {
        float w0 = W[(4 * kk + 0) * C_OUT + col];
        float w1 = W[(4 * kk + 1) * C_OUT + col];
        float w2 = W[(4 * kk + 2) * C_OUT + col];
        float w3 = W[(4 * kk + 3) * C_OUT + col];
#pragma unroll
        for (int r = 0; r < RPG; r++) {
            float4 xv = reinterpret_cast<const float4*>(&xs[r0 + r][0])[kk];
            acc[r] = fmaf(xv.x, w0, acc[r]);
            acc[r] = fmaf(xv.y, w1, acc[r]);
            acc[r] = fmaf(xv.z, w2, acc[r]);
            acc[r] = fmaf(xv.w, w3, acc[r]);
        }
    }

#pragma unroll
    for (int r = 0; r < RPG; r++) {
        int grow = rowbase + r0 + r;
        if (grow < N_NODES) H[(size_t)grow * C_OUT + col] = acc[r];
    }
}

// ---------------- aggregation: OUT[n] = dinv[n]*(dinv[n]*H[n] + sum_e dinv[s]*H[s]) + b
template <int C, bool RELU>
__global__ __launch_bounds__(256) void agg_kernel(const float* __restrict__ H,
                                                  const int* __restrict__ off,
                                                  const int* __restrict__ counts,
                                                  const int* __restrict__ csr_src,
                                                  const float* __restrict__ dinv,
                                                  const float* __restrict__ bias,
                                                  float* __restrict__ OUT) {
    int wave = threadIdx.x >> 6;
    int lane = threadIdx.x & 63;
    int n = blockIdx.x * 4 + wave;
    if (n >= N_NODES) return;

    float dn = dinv[n];
    int e0 = off[n];
    int e1 = e0 + counts[n];

    if constexpr (C == 128) {
        int c = lane * 2;
        float2 h = reinterpret_cast<const float2*>(H + (size_t)n * C)[lane];
        float2 acc;
        acc.x = dn * h.x;  // self-loop (inner weight dinv[n], outer dn applied later)
        acc.y = dn * h.y;
        for (int e = e0; e < e1; e++) {
            int s = csr_src[e];
            float ds = dinv[s];
            float2 hs = reinterpret_cast<const float2*>(H + (size_t)s * C)[lane];
            acc.x = fmaf(ds, hs.x, acc.x);
            acc.y = fmaf(ds, hs.y, acc.y);
        }
        acc.x = fmaf(acc.x, dn, bias[c]);
        acc.y = fmaf(acc.y, dn, bias[c + 1]);
        if (RELU) {
            acc.x = fmaxf(acc.x, 0.f);
            acc.y = fmaxf(acc.y, 0.f);
        }
        reinterpret_cast<float2*>(OUT + (size_t)n * C)[lane] = acc;
    } else {
        // C == 64: one channel per lane
        float h = H[(size_t)n * C + lane];
        float acc = dn * h;
        for (int e = e0; e < e1; e++) {
            int s = csr_src[e];
            float ds = dinv[s];
            acc = fmaf(ds, H[(size_t)s * C + lane], acc);
        }
        acc = fmaf(acc, dn, bias[lane]);
        if (RELU) acc = fmaxf(acc, 0.f);
        OUT[(size_t)n * C + lane] = acc;
    }
}

// ---------------- launch ----------------
extern "C" void kernel_launch(void* const* d_in, const int* in_sizes, int n_in,
                              void* d_out, int out_size, void* d_ws, size_t ws_size,
                              hipStream_t stream) {
    const float* x  = (const float*)d_in[0];
    const int*   ei = (const int*)d_in[1];
    const float* W1 = (const float*)d_in[2];
    const float* b1 = (const float*)d_in[3];
    const float* W2 = (const float*)d_in[4];
    const float* b2 = (const float*)d_in[5];
    float* out = (float*)d_out;

    char* ws = (char*)d_ws;
    auto alloc = [&](size_t bytes) -> char* {
        char* p = ws;
        ws += (bytes + 255) / 256 * 256;
        return p;
    };
    int* cnt_cur = (int*)alloc((size_t)(2 * N_NODES + 64) * 4);  // counts | cursor | total
    int* counts = cnt_cur;
    int* cursor = cnt_cur + N_NODES;
    int* total = cnt_cur + 2 * N_NODES;
    int* off = (int*)alloc((size_t)(N_NODES + 1) * 4);
    int* csr = (int*)alloc((size_t)N_EDGES * 4);
    float* dinv = (float*)alloc((size_t)N_NODES * 4);
    float* h1 = (float*)alloc((size_t)N_NODES * 128 * 4);
    float* g1 = (float*)alloc((size_t)N_NODES * 128 * 4);
    float* h2 = h1;  // layer-1 GEMM output no longer needed after agg1

    zero_int_kernel<<<(2 * N_NODES + 64 + 255) / 256, 256, 0, stream>>>(cnt_cur,
                                                                        2 * N_NODES + 64);
    count_kernel<<<(N_EDGES + 255) / 256, 256, 0, stream>>>(ei, counts);
    alloc_kernel<<<(N_NODES + 255) / 256, 256, 0, stream>>>(counts, off, dinv, total);
    fill_kernel<<<(N_EDGES + 255) / 256, 256, 0, stream>>>(ei, off, cursor, csr);

    gemm_kernel<128><<<(N_NODES + 31) / 32, 256, 0, stream>>>(x, W1, h1);
    agg_kernel<128, true><<<(N_NODES + 3) / 4, 256, 0, stream>>>(h1, off, counts, csr, dinv, b1, g1);
    gemm_kernel<64><<<(N_NODES + 31) / 32, 256, 0, stream>>>(g1, W2, h2);
    agg_kernel<64, false><<<(N_NODES + 3) / 4, 256, 0, stream>>>(h2, off, counts, csr, dinv, b2, out);
}

// Round 4
// 230.499 us; speedup vs baseline: 1.8781x; 1.4165x over previous
//
#include <hip/hip_runtime.h>
#include <hip/hip_bf16.h>
#include <math.h>

#define N_NODES 50000
#define N_EDGES 800000

typedef unsigned int uint;

__device__ __forceinline__ float bf16_lo(uint u) { return __uint_as_float(u << 16); }
__device__ __forceinline__ float bf16_hi(uint u) { return __uint_as_float(u & 0xFFFF0000u); }

// ---------------- utility ----------------
__global__ void zero_int_kernel(int* __restrict__ p, int n) {
    int i = blockIdx.x * blockDim.x + threadIdx.x;
    if (i < n) p[i] = 0;
}

// counts[dst] += 1 for every edge (self-loops added analytically later)
__global__ void count_kernel(const int* __restrict__ ei, int* __restrict__ counts) {
    int i = blockIdx.x * blockDim.x + threadIdx.x;
    if (i < N_EDGES) {
        int dst = ei[N_EDGES + i];
        atomicAdd(&counts[dst], 1);
    }
}

// Allocate disjoint CSR ranges: off[i] = global cursor bump by counts[i].
// Wave shuffle-scan + one atomic per block. Also emits dinv = rsqrt(deg+1).
__global__ __launch_bounds__(256) void alloc_kernel(const int* __restrict__ counts,
                                                    int* __restrict__ off,
                                                    float* __restrict__ dinv,
                                                    int* __restrict__ total) {
    __shared__ int wsum[4];
    __shared__ int wbase[4];
    int t = threadIdx.x;
    int lane = t & 63;
    int w = t >> 6;
    int i = blockIdx.x * 256 + t;
    int c = (i < N_NODES) ? counts[i] : 0;

    int incl = c;
#pragma unroll
    for (int o = 1; o < 64; o <<= 1) {
        int v = __shfl_up(incl, o, 64);
        if (lane >= o) incl += v;
    }
    if (lane == 63) wsum[w] = incl;
    __syncthreads();
    if (t == 0) {
        int s0 = wsum[0], s1 = wsum[1], s2 = wsum[2], s3 = wsum[3];
        int base = atomicAdd(total, s0 + s1 + s2 + s3);
        wbase[0] = base;
        wbase[1] = base + s0;
        wbase[2] = base + s0 + s1;
        wbase[3] = base + s0 + s1 + s2;
    }
    __syncthreads();
    if (i < N_NODES) {
        off[i] = wbase[w] + incl - c;
        dinv[i] = rsqrtf((float)(c + 1));
    }
}

// scatter edges into CSR grouped by dst
__global__ void fill_kernel(const int* __restrict__ ei, const int* __restrict__ off,
                            int* __restrict__ cursor, int* __restrict__ csr_src) {
    int i = blockIdx.x * blockDim.x + threadIdx.x;
    if (i < N_EDGES) {
        int src = ei[i];
        int dst = ei[N_EDGES + i];
        int pos = off[dst] + atomicAdd(&cursor[dst], 1);
        csr_src[pos] = src;
    }
}

// ---------------- GEMM: H[N,C_OUT] = bf16( dinv[n] * (X[N,128] @ W[128,C_OUT]) )
// dinv folded into the epilogue so aggregation needs no per-edge dinv loads.
template <int C_OUT>
__global__ __launch_bounds__(256) void gemm_kernel(const float* __restrict__ X,
                                                   const float* __restrict__ W,
                                                   const float* __restrict__ dinv,
                                                   __hip_bfloat16* __restrict__ H) {
    constexpr int K = 128;
    constexpr int ROWS = 32;
    constexpr int GPT = 256 / C_OUT;  // column groups per block
    constexpr int RPG = ROWS / GPT;   // rows per thread
    __shared__ float xs[ROWS][K];     // 16 KB

    int t = threadIdx.x;
    int rowbase = blockIdx.x * ROWS;

#pragma unroll
    for (int i = 0; i < 4; i++) {
        int f = i * 256 + t;
        int r = f >> 5;
        int kk = f & 31;
        float4 v;
        int grow = rowbase + r;
        if (grow < N_NODES) {
            v = reinterpret_cast<const float4*>(X + (size_t)grow * K)[kk];
        } else {
            v = make_float4(0.f, 0.f, 0.f, 0.f);
        }
        reinterpret_cast<float4*>(&xs[r][0])[kk] = v;
    }
    __syncthreads();

    int col = t % C_OUT;
    int g = t / C_OUT;
    int r0 = g * RPG;

    float acc[RPG];
#pragma unroll
    for (int r = 0; r < RPG; r++) acc[r] = 0.f;

    for (int kk = 0; kk < K / 4; kk++) {
        float w0 = W[(4 * kk + 0) * C_OUT + col];
        float w1 = W[(4 * kk + 1) * C_OUT + col];
        float w2 = W[(4 * kk + 2) * C_OUT + col];
        float w3 = W[(4 * kk + 3) * C_OUT + col];
#pragma unroll
        for (int r = 0; r < RPG; r++) {
            float4 xv = reinterpret_cast<const float4*>(&xs[r0 + r][0])[kk];
            acc[r] = fmaf(xv.x, w0, acc[r]);
            acc[r] = fmaf(xv.y, w1, acc[r]);
            acc[r] = fmaf(xv.z, w2, acc[r]);
            acc[r] = fmaf(xv.w, w3, acc[r]);
        }
    }

#pragma unroll
    for (int r = 0; r < RPG; r++) {
        int grow = rowbase + r0 + r;
        if (grow < N_NODES)
            H[(size_t)grow * C_OUT + col] = __float2bfloat16(acc[r] * dinv[grow]);
    }
}

// ---------------- aggregation: OUT[n] = dinv[n]*(H[n] + sum_e H[s]) + b
// (H pre-scaled by dinv at GEMM epilogue; H is bf16 to halve gather bytes)
template <int C, bool RELU>
__global__ __launch_bounds__(256) void agg_kernel(const __hip_bfloat16* __restrict__ H,
                                                  const int* __restrict__ off,
                                                  const int* __restrict__ counts,
                                                  const int* __restrict__ csr_src,
                                                  const float* __restrict__ dinv,
                                                  const float* __restrict__ bias,
                                                  float* __restrict__ OUT) {
    int wave = threadIdx.x >> 6;
    int lane = threadIdx.x & 63;
    int n = blockIdx.x * 4 + wave;
    if (n >= N_NODES) return;

    float dn = dinv[n];
    int e0 = off[n];
    int e1 = e0 + counts[n];

    if constexpr (C == 128) {
        // lane covers channels {2*lane, 2*lane+1} via one uint (2 bf16)
        uint u = reinterpret_cast<const uint*>(H + (size_t)n * C)[lane];
        float ax = bf16_lo(u);
        float ay = bf16_hi(u);
#pragma unroll 4
        for (int e = e0; e < e1; e++) {
            int s = csr_src[e];
            uint v = reinterpret_cast<const uint*>(H + (size_t)s * C)[lane];
            ax += bf16_lo(v);
            ay += bf16_hi(v);
        }
        float2 o;
        o.x = fmaf(ax, dn, bias[2 * lane]);
        o.y = fmaf(ay, dn, bias[2 * lane + 1]);
        if (RELU) {
            o.x = fmaxf(o.x, 0.f);
            o.y = fmaxf(o.y, 0.f);
        }
        reinterpret_cast<float2*>(OUT + (size_t)n * C)[lane] = o;
    } else {
        // C == 64: one channel per lane (2B gather per lane, 128B per row)
        float a = __bfloat162float(H[(size_t)n * C + lane]);
#pragma unroll 4
        for (int e = e0; e < e1; e++) {
            int s = csr_src[e];
            a += __bfloat162float(H[(size_t)s * C + lane]);
        }
        float o = fmaf(a, dn, bias[lane]);
        if (RELU) o = fmaxf(o, 0.f);
        OUT[(size_t)n * C + lane] = o;
    }
}

// ---------------- launch ----------------
extern "C" void kernel_launch(void* const* d_in, const int* in_sizes, int n_in,
                              void* d_out, int out_size, void* d_ws, size_t ws_size,
                              hipStream_t stream) {
    const float* x  = (const float*)d_in[0];
    const int*   ei = (const int*)d_in[1];
    const float* W1 = (const float*)d_in[2];
    const float* b1 = (const float*)d_in[3];
    const float* W2 = (const float*)d_in[4];
    const float* b2 = (const float*)d_in[5];
    float* out = (float*)d_out;

    char* ws = (char*)d_ws;
    auto alloc = [&](size_t bytes) -> char* {
        char* p = ws;
        ws += (bytes + 255) / 256 * 256;
        return p;
    };
    int* cnt_cur = (int*)alloc((size_t)(2 * N_NODES + 64) * 4);  // counts | cursor | total
    int* counts = cnt_cur;
    int* cursor = cnt_cur + N_NODES;
    int* total = cnt_cur + 2 * N_NODES;
    int* off = (int*)alloc((size_t)(N_NODES + 1) * 4);
    int* csr = (int*)alloc((size_t)N_EDGES * 4);
    float* dinv = (float*)alloc((size_t)N_NODES * 4);
    __hip_bfloat16* h1 = (__hip_bfloat16*)alloc((size_t)N_NODES * 128 * 2);  // pre-scaled bf16
    float* g1 = (float*)alloc((size_t)N_NODES * 128 * 4);                    // relu'd layer-1 out
    __hip_bfloat16* h2 = (__hip_bfloat16*)alloc((size_t)N_NODES * 64 * 2);   // pre-scaled bf16

    zero_int_kernel<<<(2 * N_NODES + 64 + 255) / 256, 256, 0, stream>>>(cnt_cur,
                                                                        2 * N_NODES + 64);
    count_kernel<<<(N_EDGES + 255) / 256, 256, 0, stream>>>(ei, counts);
    alloc_kernel<<<(N_NODES + 255) / 256, 256, 0, stream>>>(counts, off, dinv, total);
    fill_kernel<<<(N_EDGES + 255) / 256, 256, 0, stream>>>(ei, off, cursor, csr);

    gemm_kernel<128><<<(N_NODES + 31) / 32, 256, 0, stream>>>(x, W1, dinv, h1);
    agg_kernel<128, true><<<(N_NODES + 3) / 4, 256, 0, stream>>>(h1, off, counts, csr, dinv, b1, g1);
    gemm_kernel<64><<<(N_NODES + 31) / 32, 256, 0, stream>>>(g1, W2, dinv, h2);
    agg_kernel<64, false><<<(N_NODES + 3) / 4, 256, 0, stream>>>(h2, off, counts, csr, dinv, b2, out);
}

// Round 5
// 213.711 us; speedup vs baseline: 2.0257x; 1.0786x over previous
//
#include <hip/hip_runtime.h>
#include <hip/hip_bf16.h>
#include <math.h>

#define N_NODES 50000
#define N_EDGES 800000
#define NSLICE 8
#define SLICE_SZ 100000  // N_EDGES / NSLICE

typedef unsigned int uint;
typedef unsigned short ushort;

__device__ __forceinline__ float bf16_lo(uint u) { return __uint_as_float(u << 16); }
__device__ __forceinline__ float bf16_hi(uint u) { return __uint_as_float(u & 0xFFFF0000u); }
__device__ __forceinline__ uint pack_bf2(float a, float b) {
    ushort lo = __bfloat16_as_ushort(__float2bfloat16(a));
    ushort hi = __bfloat16_as_ushort(__float2bfloat16(b));
    return ((uint)hi << 16) | (uint)lo;
}

// ---------------- utility ----------------
__global__ void zero_int_kernel(int* __restrict__ p, int n) {
    int i = blockIdx.x * blockDim.x + threadIdx.x;
    if (i < n) p[i] = 0;
}

// counts[dst] += 1 per edge; atomic return value = this edge's rank within dst
__global__ void count_kernel(const int* __restrict__ ei, int* __restrict__ counts,
                             int* __restrict__ rank) {
    int i = blockIdx.x * blockDim.x + threadIdx.x;
    if (i < N_EDGES) {
        int dst = ei[N_EDGES + i];
        rank[i] = atomicAdd(&counts[dst], 1);
    }
}

// Allocate disjoint CSR ranges: off[i] = global cursor bump by counts[i].
// Wave shuffle-scan + one atomic per block. Also emits dinv = rsqrt(deg+1).
__global__ __launch_bounds__(256) void alloc_kernel(const int* __restrict__ counts,
                                                    int* __restrict__ off,
                                                    float* __restrict__ dinv,
                                                    int* __restrict__ total) {
    __shared__ int wsum[4];
    __shared__ int wbase[4];
    int t = threadIdx.x;
    int lane = t & 63;
    int w = t >> 6;
    int i = blockIdx.x * 256 + t;
    int c = (i < N_NODES) ? counts[i] : 0;

    int incl = c;
#pragma unroll
    for (int o = 1; o < 64; o <<= 1) {
        int v = __shfl_up(incl, o, 64);
        if (lane >= o) incl += v;
    }
    if (lane == 63) wsum[w] = incl;
    __syncthreads();
    if (t == 0) {
        int s0 = wsum[0], s1 = wsum[1], s2 = wsum[2], s3 = wsum[3];
        int base = atomicAdd(total, s0 + s1 + s2 + s3);
        wbase[0] = base;
        wbase[1] = base + s0;
        wbase[2] = base + s0 + s1;
        wbase[3] = base + s0 + s1 + s2;
    }
    __syncthreads();
    if (i < N_NODES) {
        off[i] = wbase[w] + incl - c;
        dinv[i] = rsqrtf((float)(c + 1));
    }
}

// pos[i] = off[dst] + rank[i]  (final CSR slot of each edge; coalesced r/w)
__global__ void pos_kernel(const int* __restrict__ ei, const int* __restrict__ off,
                           const int* __restrict__ rank, int* __restrict__ pos) {
    int i = blockIdx.x * blockDim.x + threadIdx.x;
    if (i < N_EDGES) {
        pos[i] = off[ei[N_EDGES + i]] + rank[i];
    }
}

// XCD-sliced scatter: slice s (= blockIdx%8 -> XCD s under round-robin dispatch)
// writes only csr addresses in [s*SLICE_SZ, (s+1)*SLICE_SZ) so each 64B csr line
// is owned by one XCD's L2 (kills the 55MB cross-XCD write-bounce seen in R4).
__global__ __launch_bounds__(256) void fill_kernel(const int* __restrict__ ei,
                                                   const int* __restrict__ pos,
                                                   int* __restrict__ csr) {
    int slice = blockIdx.x & (NSLICE - 1);
    int chunk = blockIdx.x / NSLICE;
    int lo = slice * SLICE_SZ;
    int hi = lo + SLICE_SZ;
    int base = chunk * 1024 + threadIdx.x * 4;
    if (base + 3 < N_EDGES) {
        int4 p = *reinterpret_cast<const int4*>(pos + base);
        int4 s = *reinterpret_cast<const int4*>(ei + base);
        if (p.x >= lo && p.x < hi) csr[p.x] = s.x;
        if (p.y >= lo && p.y < hi) csr[p.y] = s.y;
        if (p.z >= lo && p.z < hi) csr[p.z] = s.z;
        if (p.w >= lo && p.w < hi) csr[p.w] = s.w;
    } else {
        for (int e = base; e < N_EDGES && e < base + 4; e++) {
            int p = pos[e];
            if (p >= lo && p < hi) csr[p] = ei[e];
        }
    }
}

// ---------------- GEMM: H[N,C_OUT] = bf16( dinv[n] * (X[N,128] @ W[128,C_OUT]) )
// Register-tiled 4 rows x NJ*? cols per thread; rows strided by 8 with LDS row
// stride 33 float4s -> conflict-free b128 reads; W loads coalesced float4/float2.
template <int C_OUT>
__global__ __launch_bounds__(256) void gemm_kernel(const float* __restrict__ X,
                                                   const float* __restrict__ W,
                                                   const float* __restrict__ dinv,
                                                   __hip_bfloat16* __restrict__ H) {
    constexpr int K = 128;
    constexpr int ROWS = 32;
    constexpr int NJ = (C_OUT == 128) ? 4 : 2;  // cols per thread (consecutive)
    constexpr int LDX = 33;                     // float4 stride per xs row
    __shared__ float4 xs4[ROWS * LDX];          // 16.9 KB

    int t = threadIdx.x;
    int rowbase = blockIdx.x * ROWS;

    // cooperative x-tile load: 1024 float4, coalesced
#pragma unroll
    for (int i = 0; i < 4; i++) {
        int f = i * 256 + t;
        int r = f >> 5, kk = f & 31;
        float4 v = make_float4(0.f, 0.f, 0.f, 0.f);
        int gr = rowbase + r;
        if (gr < N_NODES) v = reinterpret_cast<const float4*>(X + (size_t)gr * K)[kk];
        xs4[r * LDX + kk] = v;
    }
    __syncthreads();

    int c0 = t & 31;  // col group: cols NJ*c0 .. NJ*c0+NJ-1
    int g = t >> 5;   // row group: rows g, g+8, g+16, g+24

    float acc[4][NJ];
#pragma unroll
    for (int rr = 0; rr < 4; rr++)
#pragma unroll
        for (int j = 0; j < NJ; j++) acc[rr][j] = 0.f;

#pragma unroll 8
    for (int kk = 0; kk < 32; kk++) {
        float xr[4][4];
#pragma unroll
        for (int rr = 0; rr < 4; rr++) {
            float4 xv = xs4[(g + 8 * rr) * LDX + kk];
            xr[rr][0] = xv.x; xr[rr][1] = xv.y; xr[rr][2] = xv.z; xr[rr][3] = xv.w;
        }
        float wq[4][NJ];
        if constexpr (C_OUT == 128) {
#pragma unroll
            for (int q = 0; q < 4; q++) {
                float4 wv = reinterpret_cast<const float4*>(W)[(4 * kk + q) * 32 + c0];
                wq[q][0] = wv.x; wq[q][1] = wv.y; wq[q][2] = wv.z; wq[q][3] = wv.w;
            }
        } else {
#pragma unroll
            for (int q = 0; q < 4; q++) {
                float2 wv = reinterpret_cast<const float2*>(W)[(4 * kk + q) * 32 + c0];
                wq[q][0] = wv.x; wq[q][1] = wv.y;
            }
        }
#pragma unroll
        for (int q = 0; q < 4; q++)
#pragma unroll
            for (int rr = 0; rr < 4; rr++)
#pragma unroll
                for (int j = 0; j < NJ; j++)
                    acc[rr][j] = fmaf(xr[rr][q], wq[q][j], acc[rr][j]);
    }

#pragma unroll
    for (int rr = 0; rr < 4; rr++) {
        int gr = rowbase + g + 8 * rr;
        if (gr < N_NODES) {
            float dn = dinv[gr];
            if constexpr (C_OUT == 128) {
                uint2 o;
                o.x = pack_bf2(acc[rr][0] * dn, acc[rr][1] * dn);
                o.y = pack_bf2(acc[rr][2] * dn, acc[rr][3] * dn);
                *reinterpret_cast<uint2*>(H + (size_t)gr * 128 + 4 * c0) = o;
            } else {
                uint o = pack_bf2(acc[rr][0] * dn, acc[rr][1] * dn);
                *reinterpret_cast<uint*>(H + (size_t)gr * 64 + 2 * c0) = o;
            }
        }
    }
}

// ---------------- aggregation: OUT[n] = dinv[n]*(H[n] + sum_e H[s]) + b
// (H pre-scaled by dinv at GEMM epilogue; H is bf16 to halve gather bytes)
template <int C, bool RELU>
__global__ __launch_bounds__(256) void agg_kernel(const __hip_bfloat16* __restrict__ H,
                                                  const int* __restrict__ off,
                                                  const int* __restrict__ counts,
                                                  const int* __restrict__ csr_src,
                                                  const float* __restrict__ dinv,
                                                  const float* __restrict__ bias,
                                                  float* __restrict__ OUT) {
    int wave = threadIdx.x >> 6;
    int lane = threadIdx.x & 63;
    int n = blockIdx.x * 4 + wave;
    if (n >= N_NODES) return;

    float dn = dinv[n];
    int e0 = off[n];
    int e1 = e0 + counts[n];

    if constexpr (C == 128) {
        uint u = reinterpret_cast<const uint*>(H + (size_t)n * C)[lane];
        float ax = bf16_lo(u);
        float ay = bf16_hi(u);
#pragma unroll 4
        for (int e = e0; e < e1; e++) {
            int s = csr_src[e];
            uint v = reinterpret_cast<const uint*>(H + (size_t)s * C)[lane];
            ax += bf16_lo(v);
            ay += bf16_hi(v);
        }
        float2 o;
        o.x = fmaf(ax, dn, bias[2 * lane]);
        o.y = fmaf(ay, dn, bias[2 * lane + 1]);
        if (RELU) {
            o.x = fmaxf(o.x, 0.f);
            o.y = fmaxf(o.y, 0.f);
        }
        reinterpret_cast<float2*>(OUT + (size_t)n * C)[lane] = o;
    } else {
        float a = __bfloat162float(H[(size_t)n * C + lane]);
#pragma unroll 4
        for (int e = e0; e < e1; e++) {
            int s = csr_src[e];
            a += __bfloat162float(H[(size_t)s * C + lane]);
        }
        float o = fmaf(a, dn, bias[lane]);
        if (RELU) o = fmaxf(o, 0.f);
        OUT[(size_t)n * C + lane] = o;
    }
}

// ---------------- launch ----------------
extern "C" void kernel_launch(void* const* d_in, const int* in_sizes, int n_in,
                              void* d_out, int out_size, void* d_ws, size_t ws_size,
                              hipStream_t stream) {
    const float* x  = (const float*)d_in[0];
    const int*   ei = (const int*)d_in[1];
    const float* W1 = (const float*)d_in[2];
    const float* b1 = (const float*)d_in[3];
    const float* W2 = (const float*)d_in[4];
    const float* b2 = (const float*)d_in[5];
    float* out = (float*)d_out;

    char* ws = (char*)d_ws;
    auto alloc = [&](size_t bytes) -> char* {
        char* p = ws;
        ws += (bytes + 255) / 256 * 256;
        return p;
    };
    int* counts = (int*)alloc((size_t)(N_NODES + 64) * 4);  // counts | total
    int* total = counts + N_NODES;
    int* off = (int*)alloc((size_t)(N_NODES + 1) * 4);
    int* rank = (int*)alloc((size_t)N_EDGES * 4);
    int* pos = (int*)alloc((size_t)N_EDGES * 4);
    int* csr = (int*)alloc((size_t)N_EDGES * 4);
    float* dinv = (float*)alloc((size_t)N_NODES * 4);
    __hip_bfloat16* h1 = (__hip_bfloat16*)alloc((size_t)N_NODES * 128 * 2);  // pre-scaled bf16
    float* g1 = (float*)alloc((size_t)N_NODES * 128 * 4);                    // relu'd layer-1 out
    __hip_bfloat16* h2 = (__hip_bfloat16*)alloc((size_t)N_NODES * 64 * 2);   // pre-scaled bf16

    zero_int_kernel<<<(N_NODES + 64 + 255) / 256, 256, 0, stream>>>(counts, N_NODES + 64);
    count_kernel<<<(N_EDGES + 255) / 256, 256, 0, stream>>>(ei, counts, rank);
    alloc_kernel<<<(N_NODES + 255) / 256, 256, 0, stream>>>(counts, off, dinv, total);
    pos_kernel<<<(N_EDGES + 255) / 256, 256, 0, stream>>>(ei, off, rank, pos);
    fill_kernel<<<((N_EDGES + 1023) / 1024) * NSLICE, 256, 0, stream>>>(ei, pos, csr);

    gemm_kernel<128><<<(N_NODES + 31) / 32, 256, 0, stream>>>(x, W1, dinv, h1);
    agg_kernel<128, true><<<(N_NODES + 3) / 4, 256, 0, stream>>>(h1, off, counts, csr, dinv, b1, g1);
    gemm_kernel<64><<<(N_NODES + 31) / 32, 256, 0, stream>>>(g1, W2, dinv, h2);
    agg_kernel<64, false><<<(N_NODES + 3) / 4, 256, 0, stream>>>(h2, off, counts, csr, dinv, b2, out);
}

// Round 6
// 193.612 us; speedup vs baseline: 2.2360x; 1.1038x over previous
//
#include <hip/hip_runtime.h>
#include <hip/hip_bf16.h>
#include <math.h>

#define N_NODES 50000
#define N_EDGES 800000
#define NSLICE 8
#define SLICE_SZ 100000  // N_EDGES / NSLICE

typedef unsigned int uint;
typedef unsigned short ushort;
typedef __attribute__((ext_vector_type(8))) short bf16x8;
typedef __attribute__((ext_vector_type(4))) float f32x4;

__device__ __forceinline__ float bf16_lo(uint u) { return __uint_as_float(u << 16); }
__device__ __forceinline__ float bf16_hi(uint u) { return __uint_as_float(u & 0xFFFF0000u); }
__device__ __forceinline__ ushort f2bf(float a) {
    return __bfloat16_as_ushort(__float2bfloat16(a));
}
__device__ __forceinline__ uint pack_bf2(float a, float b) {
    return ((uint)f2bf(b) << 16) | (uint)f2bf(a);
}

// ---------------- utility ----------------
__global__ void zero_int_kernel(int* __restrict__ p, int n) {
    int i = blockIdx.x * blockDim.x + threadIdx.x;
    if (i < n) p[i] = 0;
}

// counts[dst] += 1 per edge; atomic return value = this edge's rank within dst
__global__ void count_kernel(const int* __restrict__ ei, int* __restrict__ counts,
                             int* __restrict__ rank) {
    int i = blockIdx.x * blockDim.x + threadIdx.x;
    if (i < N_EDGES) {
        int dst = ei[N_EDGES + i];
        rank[i] = atomicAdd(&counts[dst], 1);
    }
}

// Allocate disjoint CSR ranges: off[i] = global cursor bump by counts[i].
__global__ __launch_bounds__(256) void alloc_kernel(const int* __restrict__ counts,
                                                    int* __restrict__ off,
                                                    float* __restrict__ dinv,
                                                    int* __restrict__ total) {
    __shared__ int wsum[4];
    __shared__ int wbase[4];
    int t = threadIdx.x;
    int lane = t & 63;
    int w = t >> 6;
    int i = blockIdx.x * 256 + t;
    int c = (i < N_NODES) ? counts[i] : 0;

    int incl = c;
#pragma unroll
    for (int o = 1; o < 64; o <<= 1) {
        int v = __shfl_up(incl, o, 64);
        if (lane >= o) incl += v;
    }
    if (lane == 63) wsum[w] = incl;
    __syncthreads();
    if (t == 0) {
        int s0 = wsum[0], s1 = wsum[1], s2 = wsum[2], s3 = wsum[3];
        int base = atomicAdd(total, s0 + s1 + s2 + s3);
        wbase[0] = base;
        wbase[1] = base + s0;
        wbase[2] = base + s0 + s1;
        wbase[3] = base + s0 + s1 + s2;
    }
    __syncthreads();
    if (i < N_NODES) {
        off[i] = wbase[w] + incl - c;
        dinv[i] = rsqrtf((float)(c + 1));
    }
}

// pos[i] = off[dst] + rank[i]  (final CSR slot of each edge; coalesced r/w)
__global__ void pos_kernel(const int* __restrict__ ei, const int* __restrict__ off,
                           const int* __restrict__ rank, int* __restrict__ pos) {
    int i = blockIdx.x * blockDim.x + threadIdx.x;
    if (i < N_EDGES) {
        pos[i] = off[ei[N_EDGES + i]] + rank[i];
    }
}

// XCD-sliced scatter (each 1/8 csr range written by one XCD's blocks -> lines
// merge in that XCD's L2 instead of bouncing via HBM)
__global__ __launch_bounds__(256) void fill_kernel(const int* __restrict__ ei,
                                                   const int* __restrict__ pos,
                                                   int* __restrict__ csr) {
    int slice = blockIdx.x & (NSLICE - 1);
    int chunk = blockIdx.x / NSLICE;
    int lo = slice * SLICE_SZ;
    int hi = lo + SLICE_SZ;
    int base = chunk * 1024 + threadIdx.x * 4;
    if (base + 3 < N_EDGES) {
        int4 p = *reinterpret_cast<const int4*>(pos + base);
        int4 s = *reinterpret_cast<const int4*>(ei + base);
        if (p.x >= lo && p.x < hi) csr[p.x] = s.x;
        if (p.y >= lo && p.y < hi) csr[p.y] = s.y;
        if (p.z >= lo && p.z < hi) csr[p.z] = s.z;
        if (p.w >= lo && p.w < hi) csr[p.w] = s.w;
    } else {
        for (int e = base; e < N_EDGES && e < base + 4; e++) {
            int p = pos[e];
            if (p >= lo && p < hi) csr[p] = ei[e];
        }
    }
}

// ---------------- conversions ----------------
// X f32 -> bf16, vectorized (float4 in, uint2 out)
__global__ __launch_bounds__(256) void cvtX_kernel(const float* __restrict__ X,
                                                   ushort* __restrict__ Xb) {
    int i = blockIdx.x * 256 + threadIdx.x;  // float4 index
    if (i < N_NODES * 32) {
        float4 v = reinterpret_cast<const float4*>(X)[i];
        uint2 o;
        o.x = pack_bf2(v.x, v.y);
        o.y = pack_bf2(v.z, v.w);
        reinterpret_cast<uint2*>(Xb)[i] = o;
    }
}

// W[k][n] f32 (K=128 rows, C cols) -> Wt[n][k] bf16 (transposed). Tiny.
__global__ void cvtW_kernel(const float* __restrict__ W, ushort* __restrict__ Wt, int C) {
    int n = threadIdx.x;
    if (n < C) {
        for (int k = 0; k < 128; k++)
            Wt[n * 128 + k] = f2bf(W[k * C + n]);
    }
}

// ---------------- MFMA GEMM: H[N,C_OUT] = bf16( dinv[n] * (Xb @ Wt^T) )
// Per wave: one 16-row tile x 64 cols (4 n-tiles of 16), K=128 via 4 MFMAs/n-tile.
// A-frag: lane(m=lane&15,q=lane>>4) reads Xb[row16+m][32kt+8q .. +7] (16B contig).
// B-frag: Wt[n][k] so lane reads Wt[nbase+nt*16+m][32kt+8q .. +7] (16B contig).
// D: row = 4q+r, col = lane&15 (guide m89-verified).
template <int C_OUT>
__global__ __launch_bounds__(256) void gemm_mfma(const ushort* __restrict__ Xb,
                                                 const ushort* __restrict__ Wt,
                                                 const float* __restrict__ dinv,
                                                 ushort* __restrict__ H) {
    int lane = threadIdx.x & 63;
    int w = threadIdx.x >> 6;
    int m = lane & 15;
    int q = lane >> 4;
    int rowTile, nbase;
    if constexpr (C_OUT == 128) {
        rowTile = blockIdx.x * 2 + (w >> 1);  // 2 row-tiles/block, 2 waves each
        nbase = (w & 1) * 64;
    } else {
        rowTile = blockIdx.x * 4 + w;  // 4 row-tiles/block, 1 wave each
        nbase = 0;
    }
    if (rowTile >= N_NODES / 16) return;  // 50000 = 16*3125, exact

    const ushort* arow = Xb + (size_t)(rowTile * 16 + m) * 128 + q * 8;
    bf16x8 afrag[4];
#pragma unroll
    for (int kt = 0; kt < 4; kt++)
        afrag[kt] = *reinterpret_cast<const bf16x8*>(arow + kt * 32);

    const ushort* brow = Wt + (size_t)(nbase + m) * 128 + q * 8;
    f32x4 acc[4];
#pragma unroll
    for (int nt = 0; nt < 4; nt++) {
        acc[nt] = {0.f, 0.f, 0.f, 0.f};
        const ushort* bp = brow + (size_t)nt * 16 * 128;
#pragma unroll
        for (int kt = 0; kt < 4; kt++) {
            bf16x8 bfrag = *reinterpret_cast<const bf16x8*>(bp + kt * 32);
            acc[nt] = __builtin_amdgcn_mfma_f32_16x16x32_bf16(afrag[kt], bfrag, acc[nt], 0, 0, 0);
        }
    }

    int rbase = rowTile * 16 + q * 4;
#pragma unroll
    for (int r = 0; r < 4; r++) {
        float dn = dinv[rbase + r];
#pragma unroll
        for (int nt = 0; nt < 4; nt++) {
            H[(size_t)(rbase + r) * C_OUT + nbase + nt * 16 + m] =
                f2bf(acc[nt][r] * dn);
        }
    }
}

// ---------------- aggregation: OUT[n] = dinv[n]*(H[n] + sum_e H[s]) + b
// H pre-scaled by dinv at GEMM epilogue, stored bf16.
// OUT_BF16: layer-1 output (g1) stored bf16 packed; else f32 (final output).
template <int C, bool RELU, bool OUT_BF16>
__global__ __launch_bounds__(256) void agg_kernel(const __hip_bfloat16* __restrict__ H,
                                                  const int* __restrict__ off,
                                                  const int* __restrict__ counts,
                                                  const int* __restrict__ csr_src,
                                                  const float* __restrict__ dinv,
                                                  const float* __restrict__ bias,
                                                  void* __restrict__ OUT) {
    int wave = threadIdx.x >> 6;
    int lane = threadIdx.x & 63;
    int n = blockIdx.x * 4 + wave;
    if (n >= N_NODES) return;

    float dn = dinv[n];
    int e0 = off[n];
    int e1 = e0 + counts[n];

    if constexpr (C == 128) {
        uint u = reinterpret_cast<const uint*>(H + (size_t)n * C)[lane];
        float ax = bf16_lo(u);
        float ay = bf16_hi(u);
#pragma unroll 4
        for (int e = e0; e < e1; e++) {
            int s = csr_src[e];
            uint v = reinterpret_cast<const uint*>(H + (size_t)s * C)[lane];
            ax += bf16_lo(v);
            ay += bf16_hi(v);
        }
        float ox = fmaf(ax, dn, bias[2 * lane]);
        float oy = fmaf(ay, dn, bias[2 * lane + 1]);
        if (RELU) {
            ox = fmaxf(ox, 0.f);
            oy = fmaxf(oy, 0.f);
        }
        if constexpr (OUT_BF16) {
            reinterpret_cast<uint*>(OUT)[(size_t)n * (C / 2) + lane] = pack_bf2(ox, oy);
        } else {
            reinterpret_cast<float2*>(OUT)[(size_t)n * (C / 2) + lane] = make_float2(ox, oy);
        }
    } else {
        float a = __bfloat162float(H[(size_t)n * C + lane]);
#pragma unroll 4
        for (int e = e0; e < e1; e++) {
            int s = csr_src[e];
            a += __bfloat162float(H[(size_t)s * C + lane]);
        }
        float o = fmaf(a, dn, bias[lane]);
        if (RELU) o = fmaxf(o, 0.f);
        if constexpr (OUT_BF16) {
            reinterpret_cast<ushort*>(OUT)[(size_t)n * C + lane] = f2bf(o);
        } else {
            reinterpret_cast<float*>(OUT)[(size_t)n * C + lane] = o;
        }
    }
}

// ---------------- launch ----------------
extern "C" void kernel_launch(void* const* d_in, const int* in_sizes, int n_in,
                              void* d_out, int out_size, void* d_ws, size_t ws_size,
                              hipStream_t stream) {
    const float* x  = (const float*)d_in[0];
    const int*   ei = (const int*)d_in[1];
    const float* W1 = (const float*)d_in[2];
    const float* b1 = (const float*)d_in[3];
    const float* W2 = (const float*)d_in[4];
    const float* b2 = (const float*)d_in[5];
    float* out = (float*)d_out;

    char* ws = (char*)d_ws;
    auto alloc = [&](size_t bytes) -> char* {
        char* p = ws;
        ws += (bytes + 255) / 256 * 256;
        return p;
    };
    int* counts = (int*)alloc((size_t)(N_NODES + 64) * 4);  // counts | total
    int* total = counts + N_NODES;
    int* off = (int*)alloc((size_t)(N_NODES + 1) * 4);
    int* rank = (int*)alloc((size_t)N_EDGES * 4);
    int* pos = (int*)alloc((size_t)N_EDGES * 4);
    int* csr = (int*)alloc((size_t)N_EDGES * 4);
    float* dinv = (float*)alloc((size_t)N_NODES * 4);
    ushort* Xb = (ushort*)alloc((size_t)N_NODES * 128 * 2);
    ushort* W1t = (ushort*)alloc((size_t)128 * 128 * 2);
    ushort* W2t = (ushort*)alloc((size_t)64 * 128 * 2);
    ushort* h1 = (ushort*)alloc((size_t)N_NODES * 128 * 2);  // dinv-scaled bf16
    ushort* g1 = (ushort*)alloc((size_t)N_NODES * 128 * 2);  // relu'd layer-1 out, bf16
    ushort* h2 = (ushort*)alloc((size_t)N_NODES * 64 * 2);   // dinv-scaled bf16

    zero_int_kernel<<<(N_NODES + 64 + 255) / 256, 256, 0, stream>>>(counts, N_NODES + 64);
    count_kernel<<<(N_EDGES + 255) / 256, 256, 0, stream>>>(ei, counts, rank);
    alloc_kernel<<<(N_NODES + 255) / 256, 256, 0, stream>>>(counts, off, dinv, total);
    pos_kernel<<<(N_EDGES + 255) / 256, 256, 0, stream>>>(ei, off, rank, pos);
    fill_kernel<<<((N_EDGES + 1023) / 1024) * NSLICE, 256, 0, stream>>>(ei, pos, csr);

    cvtX_kernel<<<(N_NODES * 32 + 255) / 256, 256, 0, stream>>>(x, Xb);
    cvtW_kernel<<<1, 128, 0, stream>>>(W1, W1t, 128);
    cvtW_kernel<<<1, 64, 0, stream>>>(W2, W2t, 64);

    gemm_mfma<128><<<(N_NODES / 16 + 1) / 2, 256, 0, stream>>>(Xb, W1t, dinv, h1);
    agg_kernel<128, true, true><<<(N_NODES + 3) / 4, 256, 0, stream>>>(
        (const __hip_bfloat16*)h1, off, counts, csr, dinv, b1, g1);
    gemm_mfma<64><<<(N_NODES / 16 + 3) / 4, 256, 0, stream>>>(g1, W2t, dinv, h2);
    agg_kernel<64, false, false><<<(N_NODES + 3) / 4, 256, 0, stream>>>(
        (const __hip_bfloat16*)h2, off, counts, csr, dinv, b2, out);
}

// Round 7
// 173.495 us; speedup vs baseline: 2.4952x; 1.1160x over previous
//
#include <hip/hip_runtime.h>
#include <hip/hip_bf16.h>
#include <math.h>

#define N_NODES 50000
#define N_EDGES 800000
#define NSLICE 8
#define SLICE_SZ 100000  // N_EDGES / NSLICE

typedef unsigned int uint;
typedef unsigned short ushort;
typedef __attribute__((ext_vector_type(8))) short bf16x8;
typedef __attribute__((ext_vector_type(4))) float f32x4;

__device__ __forceinline__ float bf16_lo(uint u) { return __uint_as_float(u << 16); }
__device__ __forceinline__ float bf16_hi(uint u) { return __uint_as_float(u & 0xFFFF0000u); }
__device__ __forceinline__ ushort f2bf(float a) {
    return __bfloat16_as_ushort(__float2bfloat16(a));
}
__device__ __forceinline__ uint pack_bf2(float a, float b) {
    return ((uint)f2bf(b) << 16) | (uint)f2bf(a);
}

// ---------------- utility ----------------
__global__ void zero_int_kernel(int* __restrict__ p, int n) {
    int i = blockIdx.x * blockDim.x + threadIdx.x;
    if (i < n) p[i] = 0;
}

// counts[dst] += 1 per edge; atomic return value = this edge's rank within dst
__global__ void count_kernel(const int* __restrict__ ei, int* __restrict__ counts,
                             int* __restrict__ rank) {
    int i = blockIdx.x * blockDim.x + threadIdx.x;
    if (i < N_EDGES) {
        int dst = ei[N_EDGES + i];
        rank[i] = atomicAdd(&counts[dst], 1);
    }
}

// Allocate disjoint CSR ranges: off[i] = global cursor bump by counts[i].
__global__ __launch_bounds__(256) void alloc_kernel(const int* __restrict__ counts,
                                                    int* __restrict__ off,
                                                    float* __restrict__ dinv,
                                                    int* __restrict__ total) {
    __shared__ int wsum[4];
    __shared__ int wbase[4];
    int t = threadIdx.x;
    int lane = t & 63;
    int w = t >> 6;
    int i = blockIdx.x * 256 + t;
    int c = (i < N_NODES) ? counts[i] : 0;

    int incl = c;
#pragma unroll
    for (int o = 1; o < 64; o <<= 1) {
        int v = __shfl_up(incl, o, 64);
        if (lane >= o) incl += v;
    }
    if (lane == 63) wsum[w] = incl;
    __syncthreads();
    if (t == 0) {
        int s0 = wsum[0], s1 = wsum[1], s2 = wsum[2], s3 = wsum[3];
        int base = atomicAdd(total, s0 + s1 + s2 + s3);
        wbase[0] = base;
        wbase[1] = base + s0;
        wbase[2] = base + s0 + s1;
        wbase[3] = base + s0 + s1 + s2;
    }
    __syncthreads();
    if (i < N_NODES) {
        off[i] = wbase[w] + incl - c;
        dinv[i] = rsqrtf((float)(c + 1));
    }
}

// pos[i] = off[dst] + rank[i]  (final CSR slot of each edge; coalesced r/w)
__global__ void pos_kernel(const int* __restrict__ ei, const int* __restrict__ off,
                           const int* __restrict__ rank, int* __restrict__ pos) {
    int i = blockIdx.x * blockDim.x + threadIdx.x;
    if (i < N_EDGES) {
        pos[i] = off[ei[N_EDGES + i]] + rank[i];
    }
}

// XCD-sliced scatter (each 1/8 csr range written by one XCD's blocks -> lines
// merge in that XCD's L2 instead of bouncing via HBM)
__global__ __launch_bounds__(256) void fill_kernel(const int* __restrict__ ei,
                                                   const int* __restrict__ pos,
                                                   int* __restrict__ csr) {
    int slice = blockIdx.x & (NSLICE - 1);
    int chunk = blockIdx.x / NSLICE;
    int lo = slice * SLICE_SZ;
    int hi = lo + SLICE_SZ;
    int base = chunk * 1024 + threadIdx.x * 4;
    if (base + 3 < N_EDGES) {
        int4 p = *reinterpret_cast<const int4*>(pos + base);
        int4 s = *reinterpret_cast<const int4*>(ei + base);
        if (p.x >= lo && p.x < hi) csr[p.x] = s.x;
        if (p.y >= lo && p.y < hi) csr[p.y] = s.y;
        if (p.z >= lo && p.z < hi) csr[p.z] = s.z;
        if (p.w >= lo && p.w < hi) csr[p.w] = s.w;
    } else {
        for (int e = base; e < N_EDGES && e < base + 4; e++) {
            int p = pos[e];
            if (p >= lo && p < hi) csr[p] = ei[e];
        }
    }
}

// ---------------- conversions ----------------
__global__ __launch_bounds__(256) void cvtX_kernel(const float* __restrict__ X,
                                                   ushort* __restrict__ Xb) {
    int i = blockIdx.x * 256 + threadIdx.x;  // float4 index
    if (i < N_NODES * 32) {
        float4 v = reinterpret_cast<const float4*>(X)[i];
        uint2 o;
        o.x = pack_bf2(v.x, v.y);
        o.y = pack_bf2(v.z, v.w);
        reinterpret_cast<uint2*>(Xb)[i] = o;
    }
}

// W[k][n] f32 (K=128 rows, C cols) -> Wt[n][k] bf16 (transposed). Tiny.
__global__ void cvtW_kernel(const float* __restrict__ W, ushort* __restrict__ Wt, int C) {
    int n = threadIdx.x;
    if (n < C) {
        for (int k = 0; k < 128; k++)
            Wt[n * 128 + k] = f2bf(W[k * C + n]);
    }
}

// ---------------- MFMA GEMM: H[N,C_OUT] = bf16( dinv[n] * (Xb @ Wt^T) )
template <int C_OUT>
__global__ __launch_bounds__(256) void gemm_mfma(const ushort* __restrict__ Xb,
                                                 const ushort* __restrict__ Wt,
                                                 const float* __restrict__ dinv,
                                                 ushort* __restrict__ H) {
    int lane = threadIdx.x & 63;
    int w = threadIdx.x >> 6;
    int m = lane & 15;
    int q = lane >> 4;
    int rowTile, nbase;
    if constexpr (C_OUT == 128) {
        rowTile = blockIdx.x * 2 + (w >> 1);
        nbase = (w & 1) * 64;
    } else {
        rowTile = blockIdx.x * 4 + w;
        nbase = 0;
    }
    if (rowTile >= N_NODES / 16) return;  // 50000 = 16*3125, exact

    const ushort* arow = Xb + (size_t)(rowTile * 16 + m) * 128 + q * 8;
    bf16x8 afrag[4];
#pragma unroll
    for (int kt = 0; kt < 4; kt++)
        afrag[kt] = *reinterpret_cast<const bf16x8*>(arow + kt * 32);

    const ushort* brow = Wt + (size_t)(nbase + m) * 128 + q * 8;
    f32x4 acc[4];
#pragma unroll
    for (int nt = 0; nt < 4; nt++) {
        acc[nt] = {0.f, 0.f, 0.f, 0.f};
        const ushort* bp = brow + (size_t)nt * 16 * 128;
#pragma unroll
        for (int kt = 0; kt < 4; kt++) {
            bf16x8 bfrag = *reinterpret_cast<const bf16x8*>(bp + kt * 32);
            acc[nt] = __builtin_amdgcn_mfma_f32_16x16x32_bf16(afrag[kt], bfrag, acc[nt], 0, 0, 0);
        }
    }

    int rbase = rowTile * 16 + q * 4;
#pragma unroll
    for (int r = 0; r < 4; r++) {
        float dn = dinv[rbase + r];
#pragma unroll
        for (int nt = 0; nt < 4; nt++) {
            H[(size_t)(rbase + r) * C_OUT + nbase + nt * 16 + m] =
                f2bf(acc[nt][r] * dn);
        }
    }
}

// ---------------- aggregation: OUT[n] = dinv[n]*(H[n] + sum_e H[s]) + b
// Deep-MLP version: one wave per node; src indices fetched 64-at-a-time with a
// single coalesced load and broadcast via __shfl; half-waves (lanes 0-31 /
// 32-63) process two different edges per slot (each half reads a full 256B
// H-row); gathers issued in unconditional batches of 8 (16 edges in flight),
// masked at accumulate. Cross-half combine via __shfl_xor(...,32) at the end.
template <int C, bool RELU, bool OUT_BF16>
__global__ __launch_bounds__(256) void agg_kernel(const __hip_bfloat16* __restrict__ Hb,
                                                  const int* __restrict__ off,
                                                  const int* __restrict__ counts,
                                                  const int* __restrict__ csr_src,
                                                  const float* __restrict__ dinv,
                                                  const float* __restrict__ bias,
                                                  void* __restrict__ OUT) {
    int wave = threadIdx.x >> 6;
    int lane = threadIdx.x & 63;
    int n = blockIdx.x * 4 + wave;
    if (n >= N_NODES) return;

    int hl = lane & 31;
    int half = lane >> 5;
    float dn = dinv[n];
    int e0 = off[n];
    int cnt = counts[n];

    if constexpr (C == 128) {
        // lane covers channels 4*hl..4*hl+3 (uint2 = 4 bf16); half-wave = 1 edge
        float a0, a1, a2, a3;
        {
            uint2 u = reinterpret_cast<const uint2*>(Hb + (size_t)n * C)[hl];
            float s0 = bf16_lo(u.x), s1 = bf16_hi(u.x), s2 = bf16_lo(u.y), s3 = bf16_hi(u.y);
            a0 = half ? 0.f : s0;  // self term counted once (half 0)
            a1 = half ? 0.f : s1;
            a2 = half ? 0.f : s2;
            a3 = half ? 0.f : s3;
        }
        for (int c = 0; c < cnt; c += 64) {
            int m = cnt - c;
            if (m > 64) m = 64;
            int my = (lane < m) ? csr_src[e0 + c + lane] : 0;
            for (int j = 0; j < m; j += 16) {
                int s[8];
                uint2 v[8];
#pragma unroll
                for (int k = 0; k < 8; k++) s[k] = __shfl(my, j + 2 * k + half, 64);
#pragma unroll
                for (int k = 0; k < 8; k++)
                    v[k] = reinterpret_cast<const uint2*>(Hb + (size_t)s[k] * C)[hl];
#pragma unroll
                for (int k = 0; k < 8; k++) {
                    if (j + 2 * k + half < m) {
                        a0 += bf16_lo(v[k].x);
                        a1 += bf16_hi(v[k].x);
                        a2 += bf16_lo(v[k].y);
                        a3 += bf16_hi(v[k].y);
                    }
                }
            }
        }
        a0 += __shfl_xor(a0, 32, 64);
        a1 += __shfl_xor(a1, 32, 64);
        a2 += __shfl_xor(a2, 32, 64);
        a3 += __shfl_xor(a3, 32, 64);
        if (half == 0) {
            float o0 = fmaf(a0, dn, bias[4 * hl + 0]);
            float o1 = fmaf(a1, dn, bias[4 * hl + 1]);
            float o2 = fmaf(a2, dn, bias[4 * hl + 2]);
            float o3 = fmaf(a3, dn, bias[4 * hl + 3]);
            if (RELU) {
                o0 = fmaxf(o0, 0.f);
                o1 = fmaxf(o1, 0.f);
                o2 = fmaxf(o2, 0.f);
                o3 = fmaxf(o3, 0.f);
            }
            if constexpr (OUT_BF16) {
                uint2 o;
                o.x = pack_bf2(o0, o1);
                o.y = pack_bf2(o2, o3);
                reinterpret_cast<uint2*>(OUT)[(size_t)n * 32 + hl] = o;
            } else {
                reinterpret_cast<float4*>(OUT)[(size_t)n * 32 + hl] =
                    make_float4(o0, o1, o2, o3);
            }
        }
    } else {
        // C == 64: lane covers channels 2*hl, 2*hl+1 (uint = 2 bf16); half-wave = 1 edge
        float a0, a1;
        {
            uint u = reinterpret_cast<const uint*>(Hb + (size_t)n * C)[hl];
            a0 = half ? 0.f : bf16_lo(u);
            a1 = half ? 0.f : bf16_hi(u);
        }
        for (int c = 0; c < cnt; c += 64) {
            int m = cnt - c;
            if (m > 64) m = 64;
            int my = (lane < m) ? csr_src[e0 + c + lane] : 0;
            for (int j = 0; j < m; j += 16) {
                int s[8];
                uint v[8];
#pragma unroll
                for (int k = 0; k < 8; k++) s[k] = __shfl(my, j + 2 * k + half, 64);
#pragma unroll
                for (int k = 0; k < 8; k++)
                    v[k] = reinterpret_cast<const uint*>(Hb + (size_t)s[k] * C)[hl];
#pragma unroll
                for (int k = 0; k < 8; k++) {
                    if (j + 2 * k + half < m) {
                        a0 += bf16_lo(v[k]);
                        a1 += bf16_hi(v[k]);
                    }
                }
            }
        }
        a0 += __shfl_xor(a0, 32, 64);
        a1 += __shfl_xor(a1, 32, 64);
        if (half == 0) {
            float o0 = fmaf(a0, dn, bias[2 * hl + 0]);
            float o1 = fmaf(a1, dn, bias[2 * hl + 1]);
            if (RELU) {
                o0 = fmaxf(o0, 0.f);
                o1 = fmaxf(o1, 0.f);
            }
            if constexpr (OUT_BF16) {
                reinterpret_cast<uint*>(OUT)[(size_t)n * 32 + hl] = pack_bf2(o0, o1);
            } else {
                reinterpret_cast<float2*>(OUT)[(size_t)n * 32 + hl] = make_float2(o0, o1);
            }
        }
    }
}

// ---------------- launch ----------------
extern "C" void kernel_launch(void* const* d_in, const int* in_sizes, int n_in,
                              void* d_out, int out_size, void* d_ws, size_t ws_size,
                              hipStream_t stream) {
    const float* x  = (const float*)d_in[0];
    const int*   ei = (const int*)d_in[1];
    const float* W1 = (const float*)d_in[2];
    const float* b1 = (const float*)d_in[3];
    const float* W2 = (const float*)d_in[4];
    const float* b2 = (const float*)d_in[5];
    float* out = (float*)d_out;

    char* ws = (char*)d_ws;
    auto alloc = [&](size_t bytes) -> char* {
        char* p = ws;
        ws += (bytes + 255) / 256 * 256;
        return p;
    };
    int* counts = (int*)alloc((size_t)(N_NODES + 64) * 4);  // counts | total
    int* total = counts + N_NODES;
    int* off = (int*)alloc((size_t)(N_NODES + 1) * 4);
    int* rank = (int*)alloc((size_t)N_EDGES * 4);
    int* pos = (int*)alloc((size_t)N_EDGES * 4);
    int* csr = (int*)alloc((size_t)N_EDGES * 4);
    float* dinv = (float*)alloc((size_t)N_NODES * 4);
    ushort* Xb = (ushort*)alloc((size_t)N_NODES * 128 * 2);
    ushort* W1t = (ushort*)alloc((size_t)128 * 128 * 2);
    ushort* W2t = (ushort*)alloc((size_t)64 * 128 * 2);
    ushort* h1 = (ushort*)alloc((size_t)N_NODES * 128 * 2);  // dinv-scaled bf16
    ushort* g1 = (ushort*)alloc((size_t)N_NODES * 128 * 2);  // relu'd layer-1 out, bf16
    ushort* h2 = (ushort*)alloc((size_t)N_NODES * 64 * 2);   // dinv-scaled bf16

    zero_int_kernel<<<(N_NODES + 64 + 255) / 256, 256, 0, stream>>>(counts, N_NODES + 64);
    count_kernel<<<(N_EDGES + 255) / 256, 256, 0, stream>>>(ei, counts, rank);
    alloc_kernel<<<(N_NODES + 255) / 256, 256, 0, stream>>>(counts, off, dinv, total);
    pos_kernel<<<(N_EDGES + 255) / 256, 256, 0, stream>>>(ei, off, rank, pos);
    fill_kernel<<<((N_EDGES + 1023) / 1024) * NSLICE, 256, 0, stream>>>(ei, pos, csr);

    cvtX_kernel<<<(N_NODES * 32 + 255) / 256, 256, 0, stream>>>(x, Xb);
    cvtW_kernel<<<1, 128, 0, stream>>>(W1, W1t, 128);
    cvtW_kernel<<<1, 64, 0, stream>>>(W2, W2t, 64);

    gemm_mfma<128><<<(N_NODES / 16 + 1) / 2, 256, 0, stream>>>(Xb, W1t, dinv, h1);
    agg_kernel<128, true, true><<<(N_NODES + 3) / 4, 256, 0, stream>>>(
        (const __hip_bfloat16*)h1, off, counts, csr, dinv, b1, g1);
    gemm_mfma<64><<<(N_NODES / 16 + 3) / 4, 256, 0, stream>>>(g1, W2t, dinv, h2);
    agg_kernel<64, false, false><<<(N_NODES + 3) / 4, 256, 0, stream>>>(
        (const __hip_bfloat16*)h2, off, counts, csr, dinv, b2, out);
}

// Round 8
// 159.875 us; speedup vs baseline: 2.7078x; 1.0852x over previous
//
#include <hip/hip_runtime.h>
#include <hip/hip_bf16.h>
#include <math.h>

#define N_NODES 50000
#define N_EDGES 800000
#define NSLICE 8
#define SLICE_SZ 100000  // N_EDGES / NSLICE

typedef unsigned int uint;
typedef unsigned short ushort;
typedef __attribute__((ext_vector_type(8))) short bf16x8;
typedef __attribute__((ext_vector_type(4))) float f32x4;

__device__ __forceinline__ float bf16_lo(uint u) { return __uint_as_float(u << 16); }
__device__ __forceinline__ float bf16_hi(uint u) { return __uint_as_float(u & 0xFFFF0000u); }
__device__ __forceinline__ ushort f2bf(float a) {
    return __bfloat16_as_ushort(__float2bfloat16(a));
}
__device__ __forceinline__ uint pack_bf2(float a, float b) {
    return ((uint)f2bf(b) << 16) | (uint)f2bf(a);
}

// ---------------- utility ----------------
__global__ void zero_int_kernel(int* __restrict__ p, int n) {
    int i = blockIdx.x * blockDim.x + threadIdx.x;
    if (i < n) p[i] = 0;
}

// counts[dst] += 1 per edge; atomic return value = this edge's rank within dst
__global__ void count_kernel(const int* __restrict__ ei, int* __restrict__ counts,
                             int* __restrict__ rank) {
    int i = blockIdx.x * blockDim.x + threadIdx.x;
    if (i < N_EDGES) {
        int dst = ei[N_EDGES + i];
        rank[i] = atomicAdd(&counts[dst], 1);
    }
}

// Allocate disjoint CSR ranges: off[i] = global cursor bump by counts[i].
__global__ __launch_bounds__(256) void alloc_kernel(const int* __restrict__ counts,
                                                    int* __restrict__ off,
                                                    float* __restrict__ dinv,
                                                    int* __restrict__ total) {
    __shared__ int wsum[4];
    __shared__ int wbase[4];
    int t = threadIdx.x;
    int lane = t & 63;
    int w = t >> 6;
    int i = blockIdx.x * 256 + t;
    int c = (i < N_NODES) ? counts[i] : 0;

    int incl = c;
#pragma unroll
    for (int o = 1; o < 64; o <<= 1) {
        int v = __shfl_up(incl, o, 64);
        if (lane >= o) incl += v;
    }
    if (lane == 63) wsum[w] = incl;
    __syncthreads();
    if (t == 0) {
        int s0 = wsum[0], s1 = wsum[1], s2 = wsum[2], s3 = wsum[3];
        int base = atomicAdd(total, s0 + s1 + s2 + s3);
        wbase[0] = base;
        wbase[1] = base + s0;
        wbase[2] = base + s0 + s1;
        wbase[3] = base + s0 + s1 + s2;
    }
    __syncthreads();
    if (i < N_NODES) {
        off[i] = wbase[w] + incl - c;
        dinv[i] = rsqrtf((float)(c + 1));
    }
}

// pos[i] = off[dst] + rank[i]  (final CSR slot of each edge; coalesced r/w)
__global__ void pos_kernel(const int* __restrict__ ei, const int* __restrict__ off,
                           const int* __restrict__ rank, int* __restrict__ pos) {
    int i = blockIdx.x * blockDim.x + threadIdx.x;
    if (i < N_EDGES) {
        pos[i] = off[ei[N_EDGES + i]] + rank[i];
    }
}

// XCD-sliced scatter (each 1/8 csr range written by one XCD's blocks -> lines
// merge in that XCD's L2 instead of bouncing via HBM)
__global__ __launch_bounds__(256) void fill_kernel(const int* __restrict__ ei,
                                                   const int* __restrict__ pos,
                                                   int* __restrict__ csr) {
    int slice = blockIdx.x & (NSLICE - 1);
    int chunk = blockIdx.x / NSLICE;
    int lo = slice * SLICE_SZ;
    int hi = lo + SLICE_SZ;
    int base = chunk * 1024 + threadIdx.x * 4;
    if (base + 3 < N_EDGES) {
        int4 p = *reinterpret_cast<const int4*>(pos + base);
        int4 s = *reinterpret_cast<const int4*>(ei + base);
        if (p.x >= lo && p.x < hi) csr[p.x] = s.x;
        if (p.y >= lo && p.y < hi) csr[p.y] = s.y;
        if (p.z >= lo && p.z < hi) csr[p.z] = s.z;
        if (p.w >= lo && p.w < hi) csr[p.w] = s.w;
    } else {
        for (int e = base; e < N_EDGES && e < base + 4; e++) {
            int p = pos[e];
            if (p >= lo && p < hi) csr[p] = ei[e];
        }
    }
}

// ---------------- W transpose+convert: Wt[n][k] = bf16(W[k][n]), parallel ----
__global__ void cvtW_kernel(const float* __restrict__ W, ushort* __restrict__ Wt, int C) {
    int i = blockIdx.x * 256 + threadIdx.x;  // i = k*C + n (coalesced read)
    if (i < 128 * C) {
        int k = i / C;
        int n = i - k * C;
        Wt[n * 128 + k] = f2bf(W[i]);
    }
}

// ---------------- MFMA GEMM: H[N,C_OUT] = bf16( dinv[n] * (A @ Wt^T) )
// A is f32 (layer 1: X) or bf16 (layer 2: g1); f32 is packed to bf16 in-register.
template <int C_OUT, bool A_F32>
__global__ __launch_bounds__(256) void gemm_mfma(const void* __restrict__ Ain,
                                                 const ushort* __restrict__ Wt,
                                                 const float* __restrict__ dinv,
                                                 ushort* __restrict__ H) {
    int lane = threadIdx.x & 63;
    int w = threadIdx.x >> 6;
    int m = lane & 15;
    int q = lane >> 4;
    int rowTile, nbase;
    if constexpr (C_OUT == 128) {
        rowTile = blockIdx.x * 2 + (w >> 1);
        nbase = (w & 1) * 64;
    } else {
        rowTile = blockIdx.x * 4 + w;
        nbase = 0;
    }
    if (rowTile >= N_NODES / 16) return;  // 50000 = 16*3125, exact

    bf16x8 afrag[4];
    if constexpr (A_F32) {
        const float* arow = (const float*)Ain + (size_t)(rowTile * 16 + m) * 128 + q * 8;
#pragma unroll
        for (int kt = 0; kt < 4; kt++) {
            float4 lo = *reinterpret_cast<const float4*>(arow + kt * 32);
            float4 hi = *reinterpret_cast<const float4*>(arow + kt * 32 + 4);
            uint4 u;
            u.x = pack_bf2(lo.x, lo.y);
            u.y = pack_bf2(lo.z, lo.w);
            u.z = pack_bf2(hi.x, hi.y);
            u.w = pack_bf2(hi.z, hi.w);
            afrag[kt] = *reinterpret_cast<bf16x8*>(&u);
        }
    } else {
        const ushort* arow = (const ushort*)Ain + (size_t)(rowTile * 16 + m) * 128 + q * 8;
#pragma unroll
        for (int kt = 0; kt < 4; kt++)
            afrag[kt] = *reinterpret_cast<const bf16x8*>(arow + kt * 32);
    }

    const ushort* brow = Wt + (size_t)(nbase + m) * 128 + q * 8;
    f32x4 acc[4];
#pragma unroll
    for (int nt = 0; nt < 4; nt++) {
        acc[nt] = {0.f, 0.f, 0.f, 0.f};
        const ushort* bp = brow + (size_t)nt * 16 * 128;
#pragma unroll
        for (int kt = 0; kt < 4; kt++) {
            bf16x8 bfrag = *reinterpret_cast<const bf16x8*>(bp + kt * 32);
            acc[nt] = __builtin_amdgcn_mfma_f32_16x16x32_bf16(afrag[kt], bfrag, acc[nt], 0, 0, 0);
        }
    }

    int rbase = rowTile * 16 + q * 4;
#pragma unroll
    for (int r = 0; r < 4; r++) {
        float dn = dinv[rbase + r];
#pragma unroll
        for (int nt = 0; nt < 4; nt++) {
            H[(size_t)(rbase + r) * C_OUT + nbase + nt * 16 + m] =
                f2bf(acc[nt][r] * dn);
        }
    }
}

// ---------------- aggregation: OUT[n] = dinv[n]*(H[n] + sum_e H[s]) + b
// Quarter-wave version: 16 lanes read one full H-row (uint4 for C=128, uint2
// for C=64), so the 4 quarter-waves process 4 edges per gather instruction.
// Src indices fetched 64-at-a-time coalesced, broadcast via __shfl; gathers
// issued in unconditional batches of 8 (32 edges in flight per wave), masked
// at accumulate. Cross-quarter combine via __shfl_xor(16|32) at the end.
template <int C, bool RELU, bool OUT_BF16>
__global__ __launch_bounds__(256) void agg_kernel(const __hip_bfloat16* __restrict__ Hb,
                                                  const int* __restrict__ off,
                                                  const int* __restrict__ counts,
                                                  const int* __restrict__ csr_src,
                                                  const float* __restrict__ dinv,
                                                  const float* __restrict__ bias,
                                                  void* __restrict__ OUT) {
    int wave = threadIdx.x >> 6;
    int lane = threadIdx.x & 63;
    int n = blockIdx.x * 4 + wave;
    if (n >= N_NODES) return;

    int ql = lane & 15;
    int quarter = lane >> 4;
    float dn = dinv[n];
    int e0 = off[n];
    int cnt = counts[n];

    if constexpr (C == 128) {
        // lane ql covers channels 8*ql .. 8*ql+7 (uint4 = 8 bf16)
        float a[8];
        {
            uint4 u = reinterpret_cast<const uint4*>(Hb + (size_t)n * C)[ql];
            a[0] = quarter ? 0.f : bf16_lo(u.x);
            a[1] = quarter ? 0.f : bf16_hi(u.x);
            a[2] = quarter ? 0.f : bf16_lo(u.y);
            a[3] = quarter ? 0.f : bf16_hi(u.y);
            a[4] = quarter ? 0.f : bf16_lo(u.z);
            a[5] = quarter ? 0.f : bf16_hi(u.z);
            a[6] = quarter ? 0.f : bf16_lo(u.w);
            a[7] = quarter ? 0.f : bf16_hi(u.w);
        }
        for (int c = 0; c < cnt; c += 64) {
            int m = cnt - c;
            if (m > 64) m = 64;
            int my = (lane < m) ? csr_src[e0 + c + lane] : 0;
            for (int j = 0; j < m; j += 32) {
                int s[8];
                uint4 v[8];
#pragma unroll
                for (int k = 0; k < 8; k++) s[k] = __shfl(my, j + 4 * k + quarter, 64);
#pragma unroll
                for (int k = 0; k < 8; k++)
                    v[k] = reinterpret_cast<const uint4*>(Hb + (size_t)s[k] * C)[ql];
#pragma unroll
                for (int k = 0; k < 8; k++) {
                    if (j + 4 * k + quarter < m) {
                        a[0] += bf16_lo(v[k].x);
                        a[1] += bf16_hi(v[k].x);
                        a[2] += bf16_lo(v[k].y);
                        a[3] += bf16_hi(v[k].y);
                        a[4] += bf16_lo(v[k].z);
                        a[5] += bf16_hi(v[k].z);
                        a[6] += bf16_lo(v[k].w);
                        a[7] += bf16_hi(v[k].w);
                    }
                }
            }
        }
#pragma unroll
        for (int r = 0; r < 8; r++) {
            a[r] += __shfl_xor(a[r], 16, 64);
            a[r] += __shfl_xor(a[r], 32, 64);
        }
        if (quarter == 0) {
            float o[8];
#pragma unroll
            for (int r = 0; r < 8; r++) {
                o[r] = fmaf(a[r], dn, bias[8 * ql + r]);
                if (RELU) o[r] = fmaxf(o[r], 0.f);
            }
            if constexpr (OUT_BF16) {
                uint4 u;
                u.x = pack_bf2(o[0], o[1]);
                u.y = pack_bf2(o[2], o[3]);
                u.z = pack_bf2(o[4], o[5]);
                u.w = pack_bf2(o[6], o[7]);
                reinterpret_cast<uint4*>(OUT)[(size_t)n * 16 + ql] = u;
            } else {
                reinterpret_cast<float4*>(OUT)[(size_t)n * 32 + 2 * ql] =
                    make_float4(o[0], o[1], o[2], o[3]);
                reinterpret_cast<float4*>(OUT)[(size_t)n * 32 + 2 * ql + 1] =
                    make_float4(o[4], o[5], o[6], o[7]);
            }
        }
    } else {
        // C == 64: lane ql covers channels 4*ql .. 4*ql+3 (uint2 = 4 bf16)
        float a[4];
        {
            uint2 u = reinterpret_cast<const uint2*>(Hb + (size_t)n * C)[ql];
            a[0] = quarter ? 0.f : bf16_lo(u.x);
            a[1] = quarter ? 0.f : bf16_hi(u.x);
            a[2] = quarter ? 0.f : bf16_lo(u.y);
            a[3] = quarter ? 0.f : bf16_hi(u.y);
        }
        for (int c = 0; c < cnt; c += 64) {
            int m = cnt - c;
            if (m > 64) m = 64;
            int my = (lane < m) ? csr_src[e0 + c + lane] : 0;
            for (int j = 0; j < m; j += 32) {
                int s[8];
                uint2 v[8];
#pragma unroll
                for (int k = 0; k < 8; k++) s[k] = __shfl(my, j + 4 * k + quarter, 64);
#pragma unroll
                for (int k = 0; k < 8; k++)
                    v[k] = reinterpret_cast<const uint2*>(Hb + (size_t)s[k] * C)[ql];
#pragma unroll
                for (int k = 0; k < 8; k++) {
                    if (j + 4 * k + quarter < m) {
                        a[0] += bf16_lo(v[k].x);
                        a[1] += bf16_hi(v[k].x);
                        a[2] += bf16_lo(v[k].y);
                        a[3] += bf16_hi(v[k].y);
                    }
                }
            }
        }
#pragma unroll
        for (int r = 0; r < 4; r++) {
            a[r] += __shfl_xor(a[r], 16, 64);
            a[r] += __shfl_xor(a[r], 32, 64);
        }
        if (quarter == 0) {
            float o[4];
#pragma unroll
            for (int r = 0; r < 4; r++) {
                o[r] = fmaf(a[r], dn, bias[4 * ql + r]);
                if (RELU) o[r] = fmaxf(o[r], 0.f);
            }
            if constexpr (OUT_BF16) {
                uint2 u;
                u.x = pack_bf2(o[0], o[1]);
                u.y = pack_bf2(o[2], o[3]);
                reinterpret_cast<uint2*>(OUT)[(size_t)n * 16 + ql] = u;
            } else {
                reinterpret_cast<float4*>(OUT)[(size_t)n * 16 + ql] =
                    make_float4(o[0], o[1], o[2], o[3]);
            }
        }
    }
}

// ---------------- launch ----------------
extern "C" void kernel_launch(void* const* d_in, const int* in_sizes, int n_in,
                              void* d_out, int out_size, void* d_ws, size_t ws_size,
                              hipStream_t stream) {
    const float* x  = (const float*)d_in[0];
    const int*   ei = (const int*)d_in[1];
    const float* W1 = (const float*)d_in[2];
    const float* b1 = (const float*)d_in[3];
    const float* W2 = (const float*)d_in[4];
    const float* b2 = (const float*)d_in[5];
    float* out = (float*)d_out;

    char* ws = (char*)d_ws;
    auto alloc = [&](size_t bytes) -> char* {
        char* p = ws;
        ws += (bytes + 255) / 256 * 256;
        return p;
    };
    int* counts = (int*)alloc((size_t)(N_NODES + 64) * 4);  // counts | total
    int* total = counts + N_NODES;
    int* off = (int*)alloc((size_t)(N_NODES + 1) * 4);
    int* rank = (int*)alloc((size_t)N_EDGES * 4);
    int* pos = (int*)alloc((size_t)N_EDGES * 4);
    int* csr = (int*)alloc((size_t)N_EDGES * 4);
    float* dinv = (float*)alloc((size_t)N_NODES * 4);
    ushort* W1t = (ushort*)alloc((size_t)128 * 128 * 2);
    ushort* W2t = (ushort*)alloc((size_t)64 * 128 * 2);
    ushort* h1 = (ushort*)alloc((size_t)N_NODES * 128 * 2);  // dinv-scaled bf16
    ushort* g1 = (ushort*)alloc((size_t)N_NODES * 128 * 2);  // relu'd layer-1 out, bf16
    ushort* h2 = (ushort*)alloc((size_t)N_NODES * 64 * 2);   // dinv-scaled bf16

    zero_int_kernel<<<(N_NODES + 64 + 255) / 256, 256, 0, stream>>>(counts, N_NODES + 64);
    count_kernel<<<(N_EDGES + 255) / 256, 256, 0, stream>>>(ei, counts, rank);
    alloc_kernel<<<(N_NODES + 255) / 256, 256, 0, stream>>>(counts, off, dinv, total);
    pos_kernel<<<(N_EDGES + 255) / 256, 256, 0, stream>>>(ei, off, rank, pos);
    fill_kernel<<<((N_EDGES + 1023) / 1024) * NSLICE, 256, 0, stream>>>(ei, pos, csr);

    cvtW_kernel<<<(128 * 128 + 255) / 256, 256, 0, stream>>>(W1, W1t, 128);
    cvtW_kernel<<<(128 * 64 + 255) / 256, 256, 0, stream>>>(W2, W2t, 64);

    gemm_mfma<128, true><<<(N_NODES / 16 + 1) / 2, 256, 0, stream>>>(x, W1t, dinv, h1);
    agg_kernel<128, true, true><<<(N_NODES + 3) / 4, 256, 0, stream>>>(
        (const __hip_bfloat16*)h1, off, counts, csr, dinv, b1, g1);
    gemm_mfma<64, false><<<(N_NODES / 16 + 3) / 4, 256, 0, stream>>>(g1, W2t, dinv, h2);
    agg_kernel<64, false, false><<<(N_NODES + 3) / 4, 256, 0, stream>>>(
        (const __hip_bfloat16*)h2, off, counts, csr, dinv, b2, out);
}